// Round 11
// baseline (131.131 us; speedup 1.0000x reference)
//
#include <hip/hip_runtime.h>
#include <hip/hip_fp16.h>
#include <cmath>

typedef _Float16 f16;
typedef __attribute__((ext_vector_type(8))) _Float16 f16x8;
typedef __attribute__((ext_vector_type(4))) _Float16 f16x4;
typedef __attribute__((ext_vector_type(4))) float f32x4;

#define EXP2F(x) __builtin_amdgcn_exp2f(x)

// ---------------------------------------------------------------------------
// Frag-linear packed layout: matrix [R,K] stored as chunks of 16 rows x 32 k
// = 512 f16 = 1 KB; chunk cid = (r>>4)*(K>>5) + (k>>5); lane
// l = (r&15) + ((k>>3)&3)*16 holds 8 f16 at l*8 — the mfma 16x16x32 operand
// fragment. Staging a chunk = ONE contiguous 1 KB wave load.
// ---------------------------------------------------------------------------
__global__ void pack3_f32_f16(
    const float* __restrict__ s0, f16* __restrict__ d0, int nc0, int kc0,
    const float* __restrict__ s1, f16* __restrict__ d1, int nc1, int kc1,
    const float* __restrict__ s2, f16* __restrict__ d2, int nc2, int kc2)
{
    int wid  = (blockIdx.x * blockDim.x + threadIdx.x) >> 6;
    int lane = threadIdx.x & 63;
    const float* s; f16* d; int cid, KC;
    if (wid < nc0)                  { s = s0; d = d0; cid = wid;             KC = kc0; }
    else if (wid < nc0 + nc1)       { s = s1; d = d1; cid = wid - nc0;       KC = kc1; }
    else if (wid < nc0 + nc1 + nc2) { s = s2; d = d2; cid = wid - nc0 - nc1; KC = kc2; }
    else return;
    int rc = cid / KC, kc = cid % KC;
    int K  = KC << 5;
    const float* src = s + (size_t)(rc * 16 + (lane & 15)) * K + kc * 32 + (lane >> 4) * 8;
    float4 v0 = *(const float4*)src;
    float4 v1 = *(const float4*)(src + 4);
    f16x8 o = { (f16)v0.x, (f16)v0.y, (f16)v0.z, (f16)v0.w,
                (f16)v1.x, (f16)v1.y, (f16)v1.z, (f16)v1.w };
    *(f16x8*)(d + (size_t)cid * 512 + lane * 8) = o;
}

__device__ __forceinline__ void store4(f16* p, const f32x4& v) {
    f16x4 o = { (f16)v[0], (f16)v[1], (f16)v[2], (f16)v[3] };
    *(f16x4*)p = o;
}
__device__ __forceinline__ void store4(float* p, const f32x4& v) {
    float4 o = { v[0], v[1], v[2], v[3] };
    *(float4*)p = o;
}

// ---------------------------------------------------------------------------
// qkv-special epilogue store (MODE 1): Q,K parts in per-head frag-linear
// chunks; V part TRANSPOSED (V^T) in per-head frag-linear chunks.
// ---------------------------------------------------------------------------
__device__ __forceinline__ void store_qkv(f16* out, int M, int row, int col,
                                          const f32x4& ov) {
    int tau = (col >= 1536) ? 2 : (col >= 768 ? 1 : 0);
    int rm  = col - tau * 768;
    int hh  = rm >> 6;
    int d   = rm & 63;
    f16* base = out + ((size_t)tau * 12 + hh) * ((size_t)M * 64);
    if (tau < 2) {
        size_t off = (size_t)(row >> 4) * 1024 + (d >> 5) * 512
                   + (size_t)((row & 15) + ((d >> 3) & 3) * 16) * 8 + (d & 7);
        store4(base + off, ov);
    } else {
#pragma unroll
        for (int i = 0; i < 4; ++i) {
            int dd = d + i;
            size_t off = (size_t)(dd >> 4) * ((size_t)M * 16)
                       + (size_t)(row >> 5) * 512
                       + (size_t)((dd & 15) + ((row >> 3) & 3) * 16) * 8 + (row & 7);
            base[off] = (f16)ov[i];
        }
    }
}

// ---------------------------------------------------------------------------
// LDS-FREE direct-fragment MFMA GEMM (packed operands): every fragment is a
// contiguous 1 KB wave load straight global->VGPR. No LDS, no barriers.
// Depth-2 register ping-pong: next k-chunk's MT+NT loads in flight during
// current chunk's MT*NT MFMAs. 4 waves as 2x2; tile (2*MT*16) x (2*NT*16).
// Same-wave-row waves reload identical A chunks -> L1 hits (same CU).
// Operand-swapped mfma: lane&15 = out row, (lane>>4)*4+reg = out col.
// ---------------------------------------------------------------------------
template <int MT, int NT, int MODE, typename OT>
__global__ __launch_bounds__(256) void gemm_f16_direct(
    const f16* __restrict__ Ap,     // packed [M/16 * K/32] chunks
    const f16* __restrict__ Wp,     // packed [N/16 * K/32] chunks
    const float* __restrict__ bias, // [N]
    OT* __restrict__ out,
    int M, int N, int K)
{
    const int tid  = threadIdx.x;
    const int lane = tid & 63;
    const int w    = tid >> 6;
    const int wr   = w >> 1;
    const int wc   = w & 1;
    const int lr   = lane & 15;
    const int lq   = lane >> 4;
    const int bm   = blockIdx.y * (2 * MT * 16);
    const int bn   = blockIdx.x * (2 * NT * 16);
    const int KC   = K >> 5;

    const f16* ga[MT];
    const f16* gb[NT];
#pragma unroll
    for (int mt = 0; mt < MT; ++mt)
        ga[mt] = Ap + (size_t)((bm >> 4) + wr * MT + mt) * KC * 512 + lane * 8;
#pragma unroll
    for (int nt = 0; nt < NT; ++nt)
        gb[nt] = Wp + (size_t)((bn >> 4) + wc * NT + nt) * KC * 512 + lane * 8;

    f32x4 acc[MT][NT] = {};
    f16x8 a0[MT], b0[NT], a1[MT], b1[NT];

#pragma unroll
    for (int mt = 0; mt < MT; ++mt) a0[mt] = *(const f16x8*)(ga[mt]);
#pragma unroll
    for (int nt = 0; nt < NT; ++nt) b0[nt] = *(const f16x8*)(gb[nt]);

    for (int k = 0; k < KC; k += 2) {
        if (k + 1 < KC) {
            const int off = (k + 1) * 512;
#pragma unroll
            for (int mt = 0; mt < MT; ++mt) a1[mt] = *(const f16x8*)(ga[mt] + off);
#pragma unroll
            for (int nt = 0; nt < NT; ++nt) b1[nt] = *(const f16x8*)(gb[nt] + off);
        }
#pragma unroll
        for (int mt = 0; mt < MT; ++mt)
#pragma unroll
            for (int nt = 0; nt < NT; ++nt)
                acc[mt][nt] = __builtin_amdgcn_mfma_f32_16x16x32_f16(
                    b0[nt], a0[mt], acc[mt][nt], 0, 0, 0);
        if (k + 2 < KC) {
            const int off = (k + 2) * 512;
#pragma unroll
            for (int mt = 0; mt < MT; ++mt) a0[mt] = *(const f16x8*)(ga[mt] + off);
#pragma unroll
            for (int nt = 0; nt < NT; ++nt) b0[nt] = *(const f16x8*)(gb[nt] + off);
        }
        if (k + 1 < KC) {
#pragma unroll
            for (int mt = 0; mt < MT; ++mt)
#pragma unroll
                for (int nt = 0; nt < NT; ++nt)
                    acc[mt][nt] = __builtin_amdgcn_mfma_f32_16x16x32_f16(
                        b1[nt], a1[mt], acc[mt][nt], 0, 0, 0);
        }
    }

#pragma unroll
    for (int mt = 0; mt < MT; ++mt) {
        int row = bm + (wr * MT + mt) * 16 + lr;
#pragma unroll
        for (int nt = 0; nt < NT; ++nt) {
            int col = bn + (wc * NT + nt) * 16 + lq * 4;
            float4 bv = *(const float4*)(bias + col);
            f32x4 ov = acc[mt][nt];
            ov[0] += bv.x; ov[1] += bv.y; ov[2] += bv.z; ov[3] += bv.w;
            if (MODE == 0) store4((OT*)out + (size_t)row * N + col, ov);
            else           store_qkv((f16*)out, M, row, col, ov);
        }
    }
}

// ---------------------------------------------------------------------------
// Packed-operand MFMA GEMM with LDS sharing (R9 pipeline) — used for GEMM2
// whose small per-wave MFMA count can't amortize duplicated direct loads.
// ---------------------------------------------------------------------------
template <int WR, int WC, int MT, int NT, typename OT>
__global__ __launch_bounds__(256) void gemm_f16_packed(
    const f16* __restrict__ Ap, const f16* __restrict__ Wp,
    const float* __restrict__ bias, OT* __restrict__ out,
    int M, int N, int K)
{
    constexpr int KK  = 2;
    constexpr int ACH = WR * MT * KK;
    constexpr int BCH = WC * NT * KK;
    constexpr int AR  = ACH / 4;
    constexpr int BR  = BCH / 4;
    __shared__ f16 Ash[2][ACH * 512];
    __shared__ f16 Bsh[2][BCH * 512];

    const int tid  = threadIdx.x;
    const int lane = tid & 63;
    const int w    = tid >> 6;
    const int wr   = w / WC;
    const int wc   = w % WC;
    const int lr   = lane & 15;
    const int lq   = lane >> 4;
    const int bm   = blockIdx.y * (WR * MT * 16);
    const int bn   = blockIdx.x * (WC * NT * 16);
    const int KC   = K >> 5;

    const f16* ga[AR];
    const f16* gb[BR];
#pragma unroll
    for (int r = 0; r < AR; ++r) {
        int s = w * AR + r, rl = s / KK, kk = s % KK;
        ga[r] = Ap + ((size_t)((bm >> 4) + rl) * KC + kk) * 512 + lane * 8;
    }
#pragma unroll
    for (int r = 0; r < BR; ++r) {
        int s = w * BR + r, rl = s / KK, kk = s % KK;
        gb[r] = Wp + ((size_t)((bn >> 4) + rl) * KC + kk) * 512 + lane * 8;
    }

    f32x4 acc[MT][NT] = {};
    f16x8 sa[AR], sb[BR];

#pragma unroll
    for (int r = 0; r < AR; ++r) sa[r] = *(const f16x8*)(ga[r]);
#pragma unroll
    for (int r = 0; r < BR; ++r) sb[r] = *(const f16x8*)(gb[r]);
#pragma unroll
    for (int r = 0; r < AR; ++r) *(f16x8*)&Ash[0][(w * AR + r) * 512 + lane * 8] = sa[r];
#pragma unroll
    for (int r = 0; r < BR; ++r) *(f16x8*)&Bsh[0][(w * BR + r) * 512 + lane * 8] = sb[r];
    __syncthreads();

    const int nk = K >> 6;
    for (int k = 0; k < nk; ++k) {
        const int cur = k & 1;
        if (k + 1 < nk) {
            const int ko = (k + 1) * KK * 512;
#pragma unroll
            for (int r = 0; r < AR; ++r) sa[r] = *(const f16x8*)(ga[r] + ko);
#pragma unroll
            for (int r = 0; r < BR; ++r) sb[r] = *(const f16x8*)(gb[r] + ko);
        }
        f16x8 af[MT][KK], bf[NT][KK];
#pragma unroll
        for (int mt = 0; mt < MT; ++mt)
#pragma unroll
            for (int kk = 0; kk < KK; ++kk)
                af[mt][kk] = *(const f16x8*)&Ash[cur][((wr * MT + mt) * KK + kk) * 512 + lane * 8];
#pragma unroll
        for (int nt = 0; nt < NT; ++nt)
#pragma unroll
            for (int kk = 0; kk < KK; ++kk)
                bf[nt][kk] = *(const f16x8*)&Bsh[cur][((wc * NT + nt) * KK + kk) * 512 + lane * 8];
#pragma unroll
        for (int kk = 0; kk < KK; ++kk)
#pragma unroll
            for (int mt = 0; mt < MT; ++mt)
#pragma unroll
                for (int nt = 0; nt < NT; ++nt)
                    acc[mt][nt] = __builtin_amdgcn_mfma_f32_16x16x32_f16(
                        bf[nt][kk], af[mt][kk], acc[mt][nt], 0, 0, 0);
        if (k + 1 < nk) {
#pragma unroll
            for (int r = 0; r < AR; ++r)
                *(f16x8*)&Ash[cur ^ 1][(w * AR + r) * 512 + lane * 8] = sa[r];
#pragma unroll
            for (int r = 0; r < BR; ++r)
                *(f16x8*)&Bsh[cur ^ 1][(w * BR + r) * 512 + lane * 8] = sb[r];
        }
        __syncthreads();
    }

#pragma unroll
    for (int mt = 0; mt < MT; ++mt) {
        int row = bm + (wr * MT + mt) * 16 + lr;
#pragma unroll
        for (int nt = 0; nt < NT; ++nt) {
            int col = bn + (wc * NT + nt) * 16 + lq * 4;
            float4 bv = *(const float4*)(bias + col);
            f32x4 ov = acc[mt][nt];
            ov[0] += bv.x; ov[1] += bv.y; ov[2] += bv.z; ov[3] += bv.w;
            store4(out + (size_t)row * N + col, ov);
        }
    }
}

// ---------------------------------------------------------------------------
// BARRIER-FREE MFMA local attention, window=128, hd=64.
// qkv in per-head frag-linear layout (Q, K chunks; V stored transposed):
// every MFMA operand is a direct contiguous 1 KB wave load. Only LDS use:
// per-wave P round-trip (swizzled, f16x4 vector writes). No __syncthreads.
// ---------------------------------------------------------------------------
#define WINDOW_SZ 128

__global__ __launch_bounds__(256) void local_attn_mfma(
    const f16* __restrict__ qkvp,  // packed per-head Q | K | V^T
    f16* __restrict__ outp,        // packed [N/16 * C/32] chunks
    int N)
{
    const int C = 768;
    __shared__ f16 Ps[4096];       // 4 waves x 1024 f16

    const int tid  = threadIdx.x;
    const int lane = tid & 63;
    const int w    = tid >> 6;
    const int r15  = lane & 15;
    const int q4   = lane >> 4;
    const int ntiles = N >> 6;
    const int h  = blockIdx.x / ntiles;
    const int i0 = (blockIdx.x % ntiles) << 6;

    const size_t hstride = (size_t)N * 64;
    const f16* Qh = qkvp + (size_t)h * hstride;
    const f16* Kh = qkvp + (size_t)(12 + h) * hstride;
    const f16* Vh = qkvp + (size_t)(24 + h) * hstride;
    const int dcStride = N * 16;   // V^T d-chunk stride

    f16x8 qf[2];
    {
        const f16* qp = Qh + (size_t)((i0 >> 4) + w) * 1024 + lane * 8;
        qf[0] = *(const f16x8*)(qp);
        qf[1] = *(const f16x8*)(qp + 512);
        const f16 qs = (f16)0.18033688f;   // 0.125 * log2(e)
#pragma unroll
        for (int j = 0; j < 8; ++j) { qf[0][j] *= qs; qf[1][j] *= qs; }
    }

    f32x4 o[4] = {};
    float m_l = -1.0e30f, l_l = 0.f;

    const int lo = (i0 >= 128) ? 0 : ((128 - i0) >> 6);
    int hi = (N + 64 - i0) >> 6; if (hi > 4) hi = 4;

    const int lssr = lane ^ ((lane >> 3) & 7);

    for (int ch = lo; ch <= hi; ++ch) {
        const int jbase = i0 - 128 + ch * 64;
        const bool need_mask = (ch == 0) || (ch == 4);

        // S^T = K @ Q^T : direct contiguous K frag loads
        f32x4 s[4] = {};
#pragma unroll
        for (int ks = 0; ks < 2; ++ks)
#pragma unroll
            for (int nt = 0; nt < 4; ++nt) {
                f16x8 kf = *(const f16x8*)(Kh + (size_t)((jbase >> 4) + nt) * 1024
                                              + ks * 512 + lane * 8);
                s[nt] = __builtin_amdgcn_mfma_f32_16x16x32_f16(kf, qf[ks], s[nt], 0, 0, 0);
            }

        if (need_mask) {
            int qg = i0 + w * 16 + r15;
#pragma unroll
            for (int nt = 0; nt < 4; ++nt)
#pragma unroll
                for (int r = 0; r < 4; ++r) {
                    int dist = qg - (jbase + nt * 16 + q4 * 4 + r);
                    if (dist < 0) dist = -dist;
                    if (dist > WINDOW_SZ) s[nt][r] = -3.0e38f;
                }
        }

        // online softmax (exp2 domain); lane owns q-row r15
        float rmax = -3.0e38f;
#pragma unroll
        for (int nt = 0; nt < 4; ++nt)
#pragma unroll
            for (int r = 0; r < 4; ++r) rmax = fmaxf(rmax, s[nt][r]);
        rmax = fmaxf(rmax, __shfl_xor(rmax, 16));
        rmax = fmaxf(rmax, __shfl_xor(rmax, 32));
        float mn = fmaxf(m_l, rmax);
        float al = EXP2F(m_l - mn);
        m_l = mn;
        float rs = 0.f;
#pragma unroll
        for (int nt = 0; nt < 4; ++nt)
#pragma unroll
            for (int r = 0; r < 4; ++r) {
                float pv = EXP2F(s[nt][r] - mn);
                s[nt][r] = pv;
                rs += pv;
            }
        rs += __shfl_xor(rs, 16);
        rs += __shfl_xor(rs, 32);
        l_l = l_l * al + rs;
#pragma unroll
        for (int nd = 0; nd < 4; ++nd)
#pragma unroll
            for (int r = 0; r < 4; ++r) o[nd][r] *= al;

        // P -> Ps (per-wave, swizzled B-frag layout; f16x4 vector writes)
#pragma unroll
        for (int nt = 0; nt < 4; ++nt) {
            int cs = nt >> 1;
            int ls = ((nt & 1) * 2 + (q4 >> 1)) * 16 + r15;
            int lss = ls ^ ((ls >> 3) & 7);
            f16x4 pv4 = { (f16)s[nt][0], (f16)s[nt][1], (f16)s[nt][2], (f16)s[nt][3] };
            *(f16x4*)&Ps[(w * 2 + cs) * 512 + lss * 8 + (q4 & 1) * 4] = pv4;
        }

        // O^T += V^T @ P^T : direct contiguous V^T frag loads
#pragma unroll
        for (int cs = 0; cs < 2; ++cs) {
            f16x8 pf = *(const f16x8*)&Ps[(w * 2 + cs) * 512 + lssr * 8];
#pragma unroll
            for (int nd = 0; nd < 4; ++nd) {
                f16x8 vf = *(const f16x8*)(Vh + (size_t)nd * dcStride
                                              + (size_t)((jbase >> 5) + cs) * 512 + lane * 8);
                o[nd] = __builtin_amdgcn_mfma_f32_16x16x32_f16(vf, pf, o[nd], 0, 0, 0);
            }
        }
    }

    // epilogue: packed chunks for GEMM2
    float inv = 1.0f / l_l;
    const int KC2 = C >> 5;
    const int rc  = (i0 >> 4) + w;
#pragma unroll
    for (int nd = 0; nd < 4; ++nd) {
        int col = h * 64 + nd * 16 + q4 * 4;
        int kc  = col >> 5;
        int lp  = r15 + ((col >> 3) & 3) * 16;
        f16x4 ov = { (f16)(o[nd][0] * inv), (f16)(o[nd][1] * inv),
                     (f16)(o[nd][2] * inv), (f16)(o[nd][3] * inv) };
        *(f16x4*)(outp + ((size_t)rc * KC2 + kc) * 512 + lp * 8 + (col & 7)) = ov;
    }
}

// ---------------------------------------------------------------------------
extern "C" void kernel_launch(void* const* d_in, const int* in_sizes, int n_in,
                              void* d_out, int out_size, void* d_ws, size_t ws_size,
                              hipStream_t stream) {
    (void)n_in; (void)out_size; (void)ws_size;
    const float* x      = (const float*)d_in[0];
    const float* qkv_w  = (const float*)d_in[1];
    const float* qkv_b  = (const float*)d_in[2];
    const float* proj_w = (const float*)d_in[3];
    const float* proj_b = (const float*)d_in[4];
    float* outp = (float*)d_out;

    const int C    = in_sizes[2] / 3;     // 768
    const int Nseq = in_sizes[0] / C;     // 4096
    const int C3   = 3 * C;               // 2304
    const int KC   = C >> 5;              // 24

    char* ws = (char*)d_ws;
    f16* qkv_p = (f16*)ws;   ws += (size_t)Nseq * C3 * 2;   // per-head packed Q|K|V^T
    f16* xp    = (f16*)ws;   ws += (size_t)Nseq * C * 2;    // packed (reused as attn_p)
    f16* wqp   = (f16*)ws;   ws += (size_t)C3 * C * 2;      // packed
    f16* wpp   = (f16*)ws;                                   // packed
    f16* attn_p = xp;   // alias: xp dead after GEMM1

    dim3 blk(256);
    {
        int nc0 = (Nseq / 16) * KC;
        int nc1 = (C3 / 16) * KC;
        int nc2 = (C / 16) * KC;
        int nwaves = nc0 + nc1 + nc2;
        pack3_f32_f16<<<dim3((nwaves + 3) / 4), blk, 0, stream>>>(
            x, xp, nc0, KC, qkv_w, wqp, nc1, KC, proj_w, wpp, nc2, KC);
    }
    // qkv (per-head packed; V transposed) = x @ qkv_w^T + qkv_b — LDS-free
    gemm_f16_direct<4, 4, 1, f16><<<dim3(C3 / 128, Nseq / 128), blk, 0, stream>>>(
        xp, wqp, qkv_b, (f16*)qkv_p, Nseq, C3, C);
    // barrier-free banded attention -> packed f16
    local_attn_mfma<<<dim3((C / 64) * (Nseq / 64)), blk, 0, stream>>>(
        qkv_p, attn_p, Nseq);
    // out (f32 row-major) = attn @ proj_w^T + proj_b — LDS pipeline
    gemm_f16_packed<2, 2, 2, 2, float><<<dim3(C / 64, Nseq / 64), blk, 0, stream>>>(
        attn_p, wpp, proj_b, outp, Nseq, C, C);
}